// Round 2
// baseline (535.573 us; speedup 1.0000x reference)
//
#include <hip/hip_runtime.h>
#include <hip/hip_bf16.h>

// 3-layer GraphConv (PyG semantics) + softmax, 100k nodes, 1.6M edges.
//   out_i = lin_rel(sum_{j->i} x_j) + lin_root(x_i)
// Dtypes (JAX x64 disabled): all floats are float32, edge_index is int32,
// output is float32. Round-1 NaN came from misreading f32 data as bf16.
// Optimization: transform-then-scatter (linear commutes with segment_sum), so
// scatter width is Fout (32/16/2) instead of Fin (64/32/16).

// Computes, per node n:
//   t[n]   = act(x[n]) @ Wrel          (edge-message precursor)
//   acc[n] = act(x[n]) @ Wroot + bias  (accumulator init = root term)
// act = relu if RELU else identity. Weights staged in LDS (broadcast reads).
template <int Fin, int Fout, bool RELU>
__global__ void transform_kernel(const float* __restrict__ x,
                                 const float* __restrict__ Wrel,
                                 const float* __restrict__ Wroot,
                                 const float* __restrict__ bias,
                                 float* __restrict__ t,
                                 float* __restrict__ acc,
                                 int N) {
    __shared__ float sRel[Fin * Fout];
    __shared__ float sRoot[Fin * Fout];
    __shared__ float sB[Fout];
    for (int i = threadIdx.x; i < Fin * Fout; i += blockDim.x) {
        sRel[i]  = Wrel[i];
        sRoot[i] = Wroot[i];
    }
    if (threadIdx.x < Fout) sB[threadIdx.x] = bias[threadIdx.x];
    __syncthreads();

    int n = blockIdx.x * blockDim.x + threadIdx.x;
    if (n >= N) return;

    float xi[Fin];
#pragma unroll
    for (int k = 0; k < Fin; ++k) {
        float v = x[(long)n * Fin + k];
        if (RELU) v = fmaxf(v, 0.0f);
        xi[k] = v;
    }

    for (int f = 0; f < Fout; ++f) {
        float a = 0.0f, r = 0.0f;
#pragma unroll
        for (int k = 0; k < Fin; ++k) {
            a = fmaf(xi[k], sRel[k * Fout + f], a);
            r = fmaf(xi[k], sRoot[k * Fout + f], r);
        }
        t[(long)n * Fout + f]   = a;
        acc[(long)n * Fout + f] = r + sB[f];
    }
}

// F lanes cooperate on one edge: contiguous F*4B gather from t[src], contiguous
// F*4B atomic region at acc[dst]. F is a power of two.
template <int F>
__global__ void scatter_kernel(const float* __restrict__ t,
                               const int* __restrict__ src,
                               const int* __restrict__ dst,
                               float* __restrict__ acc,
                               int nE) {
    int tid = blockIdx.x * blockDim.x + threadIdx.x;
    int e = tid / F;
    if (e >= nE) return;
    int f = tid & (F - 1);
    int s = src[e];
    int d = dst[e];
    atomicAdd(acc + (long)d * F + f, t[(long)s * F + f]);
}

__global__ void softmax2_kernel(const float* __restrict__ h,
                                float* __restrict__ out, int N) {
    int n = blockIdx.x * blockDim.x + threadIdx.x;
    if (n >= N) return;
    float a = h[2 * n], b = h[2 * n + 1];
    float m = fmaxf(a, b);
    float ea = __expf(a - m), eb = __expf(b - m);
    float inv = 1.0f / (ea + eb);
    out[2 * n]     = ea * inv;
    out[2 * n + 1] = eb * inv;
}

extern "C" void kernel_launch(void* const* d_in, const int* in_sizes, int n_in,
                              void* d_out, int out_size, void* d_ws, size_t ws_size,
                              hipStream_t stream) {
    const float* z      = (const float*)d_in[0];
    const int*   ei     = (const int*)d_in[1];
    const float* Wrel1  = (const float*)d_in[2];
    const float* Wroot1 = (const float*)d_in[3];
    const float* b1     = (const float*)d_in[4];
    const float* Wrel2  = (const float*)d_in[5];
    const float* Wroot2 = (const float*)d_in[6];
    const float* b2     = (const float*)d_in[7];
    const float* Wrel3  = (const float*)d_in[8];
    const float* Wroot3 = (const float*)d_in[9];
    const float* b3     = (const float*)d_in[10];

    const int N  = in_sizes[0] / 64;   // 100000
    const int nE = in_sizes[1] / 2;    // 1600000
    const int* src = ei;
    const int* dst = ei + nE;

    // Workspace layout (two ping-pong regions of N*32 floats = 12.8 MB each):
    //   regionA: t1[N*32]  ->  { t2[N*16] | h2[N*16] }
    //   regionB: h1[N*32]  ->  { t3[N*2]  | h3[N*2]  }
    float* regionA = (float*)d_ws;
    float* regionB = regionA + (long)N * 32;
    float* t1 = regionA;
    float* h1 = regionB;
    float* t2 = regionA;
    float* h2 = regionA + (long)N * 16;
    float* t3 = regionB;
    float* h3 = regionB + (long)N * 2;

    const int B = 256;
    const int nodeBlocks = (N + B - 1) / B;

    // Layer 1: 64 -> 32
    transform_kernel<64, 32, false>
        <<<nodeBlocks, B, 0, stream>>>(z, Wrel1, Wroot1, b1, t1, h1, N);
    scatter_kernel<32><<<((long)nE * 32 + B - 1) / B, B, 0, stream>>>(t1, src, dst, h1, nE);

    // Layer 2: 32 -> 16 (relu on input)
    transform_kernel<32, 16, true>
        <<<nodeBlocks, B, 0, stream>>>(h1, Wrel2, Wroot2, b2, t2, h2, N);
    scatter_kernel<16><<<((long)nE * 16 + B - 1) / B, B, 0, stream>>>(t2, src, dst, h2, nE);

    // Layer 3: 16 -> 2 (relu on input)
    transform_kernel<16, 2, true>
        <<<nodeBlocks, B, 0, stream>>>(h2, Wrel3, Wroot3, b3, t3, h3, N);
    scatter_kernel<2><<<((long)nE * 2 + B - 1) / B, B, 0, stream>>>(t3, src, dst, h3, nE);

    // Softmax over 2 classes -> f32 output
    softmax2_kernel<<<nodeBlocks, B, 0, stream>>>(h3, (float*)d_out, N);
}

// Round 3
// 482.787 us; speedup vs baseline: 1.1093x; 1.1093x over previous
//
#include <hip/hip_runtime.h>
#include <hip/hip_bf16.h>

// 3-layer GraphConv (PyG semantics) + softmax, 100k nodes, 1.6M edges, all f32.
//   out_i = lin_rel(sum_{j->i} x_j) + lin_root(x_i)
// R2 counters: f32 atomics execute past L2 (WRITE_SIZE == 4B*atomic count),
// ~306G atomics/s ceiling, scatter kernels = 93% of runtime.
// R3: pull-gather over per-call CSR (hist + scan + bucket), zero f32 atomics.

// ---------------- transform: t = act(x)@Wrel ; acc = act(x)@Wroot + b -------
template <int Fin, int Fout, bool RELU>
__global__ void transform_kernel(const float* __restrict__ x,
                                 const float* __restrict__ Wrel,
                                 const float* __restrict__ Wroot,
                                 const float* __restrict__ bias,
                                 float* __restrict__ t,
                                 float* __restrict__ acc,
                                 int N) {
    __shared__ float sRel[Fin * Fout];
    __shared__ float sRoot[Fin * Fout];
    __shared__ float sB[Fout];
    for (int i = threadIdx.x; i < Fin * Fout; i += blockDim.x) {
        sRel[i]  = Wrel[i];
        sRoot[i] = Wroot[i];
    }
    if (threadIdx.x < Fout) sB[threadIdx.x] = bias[threadIdx.x];
    __syncthreads();

    int n = blockIdx.x * blockDim.x + threadIdx.x;
    if (n >= N) return;

    float xi[Fin];
#pragma unroll
    for (int k = 0; k < Fin; ++k) {
        float v = x[(long)n * Fin + k];
        if (RELU) v = fmaxf(v, 0.0f);
        xi[k] = v;
    }

    for (int f = 0; f < Fout; ++f) {
        float a = 0.0f, r = 0.0f;
#pragma unroll
        for (int k = 0; k < Fin; ++k) {
            a = fmaf(xi[k], sRel[k * Fout + f], a);
            r = fmaf(xi[k], sRoot[k * Fout + f], r);
        }
        t[(long)n * Fout + f]   = a;
        acc[(long)n * Fout + f] = r + sB[f];
    }
}

// ---------------- CSR build ------------------------------------------------
__global__ void hist_kernel(const int* __restrict__ dst, int* __restrict__ counts, int nE) {
    int e = blockIdx.x * blockDim.x + threadIdx.x;
    if (e < nE) atomicAdd(&counts[dst[e]], 1);
}

__global__ void block_sum_kernel(const int* __restrict__ counts, int* __restrict__ partials, int N) {
    __shared__ int s[256];
    int i = blockIdx.x * 256 + threadIdx.x;
    s[threadIdx.x] = (i < N) ? counts[i] : 0;
    __syncthreads();
    for (int off = 128; off > 0; off >>= 1) {
        if (threadIdx.x < off) s[threadIdx.x] += s[threadIdx.x + off];
        __syncthreads();
    }
    if (threadIdx.x == 0) partials[blockIdx.x] = s[0];
}

// exclusive scan over <=512 partials, one block of 512 threads
__global__ void scan_top_kernel(int* __restrict__ partials, int nb) {
    __shared__ int s[512];
    int t = threadIdx.x;
    s[t] = (t < nb) ? partials[t] : 0;
    __syncthreads();
    for (int off = 1; off < 512; off <<= 1) {
        int v = (t >= off) ? s[t - off] : 0;
        __syncthreads();
        s[t] += v;
        __syncthreads();
    }
    if (t < nb) partials[t] = (t == 0) ? 0 : s[t - 1];
}

// exclusive scan of counts within each 256-block + partials offset -> rowptr.
// Also re-initializes counts[] as the bucket cursor (= rowptr value).
__global__ void scan_final_kernel(int* __restrict__ counts,           // in: counts, out: cursor
                                  const int* __restrict__ partials,
                                  int* __restrict__ rowptr,
                                  int N, int nE) {
    __shared__ int s[256];
    int t = threadIdx.x;
    int i = blockIdx.x * 256 + t;
    int v = (i < N) ? counts[i] : 0;
    s[t] = v;
    __syncthreads();
    for (int off = 1; off < 256; off <<= 1) {
        int u = (t >= off) ? s[t - off] : 0;
        __syncthreads();
        s[t] += u;
        __syncthreads();
    }
    if (i < N) {
        int ex = partials[blockIdx.x] + s[t] - v;  // exclusive
        rowptr[i] = ex;
        counts[i] = ex;                            // cursor init
    }
    if (i == 0) rowptr[N] = nE;
}

__global__ void bucket_kernel(const int* __restrict__ src, const int* __restrict__ dst,
                              int* __restrict__ cursor, int* __restrict__ srcs_sorted, int nE) {
    int e = blockIdx.x * blockDim.x + threadIdx.x;
    if (e < nE) {
        int pos = atomicAdd(&cursor[dst[e]], 1);
        srcs_sorted[pos] = src[e];
    }
}

// ---------------- pull aggregation: out[n] = rootacc[n] + sum_{e in row n} t[srcs[e]]
// F lanes per node (F power of 2). 4-way unrolled gather for MLP.
template <int F, bool SOFTMAX>
__global__ void gather_agg_kernel(const float* __restrict__ t,
                                  const int* __restrict__ rowptr,
                                  const int* __restrict__ srcs,
                                  const float* __restrict__ rootacc,
                                  float* __restrict__ out, int N) {
    int tid = blockIdx.x * blockDim.x + threadIdx.x;
    int n = tid / F;
    if (n >= N) return;
    int f = tid & (F - 1);
    int beg = rowptr[n], end = rowptr[n + 1];
    float sum = 0.0f;
    int e = beg;
    for (; e + 4 <= end; e += 4) {
        int s0 = srcs[e], s1 = srcs[e + 1], s2 = srcs[e + 2], s3 = srcs[e + 3];
        float v0 = t[(long)s0 * F + f];
        float v1 = t[(long)s1 * F + f];
        float v2 = t[(long)s2 * F + f];
        float v3 = t[(long)s3 * F + f];
        sum += v0 + v1 + v2 + v3;
    }
    for (; e < end; ++e) sum += t[(long)srcs[e] * F + f];

    float v = rootacc[(long)n * F + f] + sum;
    if (!SOFTMAX) {
        out[(long)n * F + f] = v;
    } else {
        // F==2: partner lane holds the other logit
        float o = __shfl_xor(v, 1, 64);
        float m = fmaxf(v, o);
        float ev = __expf(v - m), eo = __expf(o - m);
        out[(long)n * F + f] = ev / (ev + eo);
    }
}

// ---------------- fallback (R2 atomic path) --------------------------------
template <int F>
__global__ void scatter_kernel(const float* __restrict__ t,
                               const int* __restrict__ src,
                               const int* __restrict__ dst,
                               float* __restrict__ acc, int nE) {
    int tid = blockIdx.x * blockDim.x + threadIdx.x;
    int e = tid / F;
    if (e >= nE) return;
    int f = tid & (F - 1);
    atomicAdd(acc + (long)dst[e] * F + f, t[(long)src[e] * F + f]);
}

__global__ void softmax2_kernel(const float* __restrict__ h, float* __restrict__ out, int N) {
    int n = blockIdx.x * blockDim.x + threadIdx.x;
    if (n >= N) return;
    float a = h[2 * n], b = h[2 * n + 1];
    float m = fmaxf(a, b);
    float ea = __expf(a - m), eb = __expf(b - m);
    float inv = 1.0f / (ea + eb);
    out[2 * n] = ea * inv;
    out[2 * n + 1] = eb * inv;
}

extern "C" void kernel_launch(void* const* d_in, const int* in_sizes, int n_in,
                              void* d_out, int out_size, void* d_ws, size_t ws_size,
                              hipStream_t stream) {
    const float* z      = (const float*)d_in[0];
    const int*   ei     = (const int*)d_in[1];
    const float* Wrel1  = (const float*)d_in[2];
    const float* Wroot1 = (const float*)d_in[3];
    const float* b1     = (const float*)d_in[4];
    const float* Wrel2  = (const float*)d_in[5];
    const float* Wroot2 = (const float*)d_in[6];
    const float* b2     = (const float*)d_in[7];
    const float* Wrel3  = (const float*)d_in[8];
    const float* Wroot3 = (const float*)d_in[9];
    const float* b3     = (const float*)d_in[10];

    const int N  = in_sizes[0] / 64;   // 100000
    const int nE = in_sizes[1] / 2;    // 1600000
    const int* src = ei;
    const int* dst = ei + nE;

    // Float regions (ping-pong, 12.8 MB each):
    //   regionA: t1[N*32] -> { t2[N*16] | h2[N*16] }
    //   regionB: h1[N*32] -> { t3[N*2]  | h3[N*2]  }
    float* regionA = (float*)d_ws;
    float* regionB = regionA + (size_t)N * 32;
    float* t1 = regionA;
    float* h1 = regionB;
    float* t2 = regionA;
    float* h2 = regionA + (size_t)N * 16;
    float* t3 = regionB;
    float* h3 = regionB + (size_t)N * 2;

    // Int region (CSR): counts/cursor[N], rowptr[N+1], partials[512], srcs_sorted[nE]
    int* ibase       = (int*)(regionB + (size_t)N * 32);
    int* counts      = ibase;                 // doubles as cursor after scan_final
    int* rowptr      = counts + N;
    int* partials    = rowptr + N + 1;
    int* srcs_sorted = partials + 512;

    size_t needed = (size_t)N * 64 * sizeof(float)
                  + ((size_t)N + (size_t)N + 1 + 512 + (size_t)nE) * sizeof(int);

    const int B = 256;
    const int nodeBlocks = (N + B - 1) / B;        // 391
    const int edgeBlocks = (nE + B - 1) / B;       // 6250

    if (ws_size >= needed) {
        // ---- CSR build (per call; ws is re-poisoned between calls) ----
        hipMemsetAsync(counts, 0, (size_t)N * sizeof(int), stream);
        hist_kernel<<<edgeBlocks, B, 0, stream>>>(dst, counts, nE);
        block_sum_kernel<<<nodeBlocks, B, 0, stream>>>(counts, partials, N);
        scan_top_kernel<<<1, 512, 0, stream>>>(partials, nodeBlocks);
        scan_final_kernel<<<nodeBlocks, B, 0, stream>>>(counts, partials, rowptr, N, nE);
        bucket_kernel<<<edgeBlocks, B, 0, stream>>>(src, dst, counts, srcs_sorted, nE);

        // ---- Layer 1: 64 -> 32 ----
        transform_kernel<64, 32, false><<<nodeBlocks, B, 0, stream>>>(z, Wrel1, Wroot1, b1, t1, h1, N);
        gather_agg_kernel<32, false><<<((size_t)N * 32 + B - 1) / B, B, 0, stream>>>(
            t1, rowptr, srcs_sorted, h1, h1, N);

        // ---- Layer 2: 32 -> 16 ----
        transform_kernel<32, 16, true><<<nodeBlocks, B, 0, stream>>>(h1, Wrel2, Wroot2, b2, t2, h2, N);
        gather_agg_kernel<16, false><<<((size_t)N * 16 + B - 1) / B, B, 0, stream>>>(
            t2, rowptr, srcs_sorted, h2, h2, N);

        // ---- Layer 3: 16 -> 2, softmax fused ----
        transform_kernel<16, 2, true><<<nodeBlocks, B, 0, stream>>>(h2, Wrel3, Wroot3, b3, t3, h3, N);
        gather_agg_kernel<2, true><<<((size_t)N * 2 + B - 1) / B, B, 0, stream>>>(
            t3, rowptr, srcs_sorted, h3, (float*)d_out, N);
    } else {
        // ---- fallback: R2 atomic-scatter path ----
        transform_kernel<64, 32, false><<<nodeBlocks, B, 0, stream>>>(z, Wrel1, Wroot1, b1, t1, h1, N);
        scatter_kernel<32><<<((size_t)nE * 32 + B - 1) / B, B, 0, stream>>>(t1, src, dst, h1, nE);
        transform_kernel<32, 16, true><<<nodeBlocks, B, 0, stream>>>(h1, Wrel2, Wroot2, b2, t2, h2, N);
        scatter_kernel<16><<<((size_t)nE * 16 + B - 1) / B, B, 0, stream>>>(t2, src, dst, h2, nE);
        transform_kernel<16, 2, true><<<nodeBlocks, B, 0, stream>>>(h2, Wrel3, Wroot3, b3, t3, h3, N);
        scatter_kernel<2><<<((size_t)nE * 2 + B - 1) / B, B, 0, stream>>>(t3, src, dst, h3, nE);
        softmax2_kernel<<<nodeBlocks, B, 0, stream>>>(h3, (float*)d_out, N);
    }
}